// Round 12
// baseline (173.655 us; speedup 1.0000x reference)
//
#include <hip/hip_runtime.h>
#include <hip/hip_bf16.h>

typedef __hip_bfloat16 bf16;
typedef __attribute__((ext_vector_type(8))) short short8;
typedef __attribute__((ext_vector_type(4))) float f32x4;
typedef __attribute__((ext_vector_type(2))) float f32x2;

#define NB    20000
#define BATCH 2
#define HDIM  128
#define KNBR  32
#define NCLS  40
#define NLAYER 3
#define BM    64          // rows per tile: embed/cls kernels
#define LBM   32          // rows per tile: layer kernel (4 blocks/CU)
#define LDP   136         // padded LDS row stride (bf16 elems): 272 B, 16B-aligned
#define NTILES 625        // 64-row tiles over 40000 nodes (embed/cls)
#define LTPH   625        // 32-row layer tiles per batch half (20000/32, exact)
#define LGRID  1256       // 8*157, batch-XCD swizzled with guards
#define H8SCALE 256.0f    // power-of-2 shift into fp8 normal range
#define H8INV  (1.0f/256.0f)

__device__ __forceinline__ short f2bf(float v) {
    return __builtin_bit_cast(short, __float2bfloat16(v));
}
__device__ __forceinline__ unsigned char f2fp8(float v) {
    return (unsigned char)(__builtin_amdgcn_cvt_pk_fp8_f32(v, 0.0f, 0, false) & 0xff);
}

// ---------------- weight pre-pack: f32 [K][N] -> bf16 fragment layout ----------------
__global__ void pack_weights(const float* __restrict__ Wemb, const float* __restrict__ gW,
                             const float* __restrict__ gB, const float* __restrict__ W1,
                             const float* __restrict__ W2, short* __restrict__ pw) {
    const int idx = blockIdx.x * 256 + threadIdx.x;
    if (idx < 8 * 16384) {
        const int m = idx >> 14, e = idx & 16383;
        const float* src = (m == 0) ? Wemb
                         : (m <= 3) ? gW + (size_t)(m - 1) * 16384
                         : (m <= 6) ? gB + (size_t)(m - 4) * 16384
                         : W1;
        const int k = e >> 7, n = e & 127;
        pw[m * 16384 + (((k >> 3) * 128 + n) << 3) + (k & 7)] = f2bf(src[e]);
    } else {
        const int e = idx - 8 * 16384;
        if (e < 128 * NCLS) {
            const int k = e / NCLS, n = e - k * NCLS;
            pw[8 * 16384 + ((k >> 3) * NCLS + n) * 8 + (k & 7)] = f2bf(W2[e]);
        }
    }
}

// ---------------- embed: h0 = (x @ Wemb) / rowsum(x); writes bf16 h + fp8 h8 ----------------
__global__ __launch_bounds__(512, 4) void embed_gemm(const float* __restrict__ x,
                                                     const short* __restrict__ pwE,
                                                     bf16* __restrict__ h0,
                                                     unsigned char* __restrict__ h8) {
    __shared__ short sx[BM * LDP];
    const int t = threadIdx.x;
    const int row0 = blockIdx.x * BM;

    {
        const int r = t >> 3, fs = (t & 7) * 16;
        const float4* p = (const float4*)(x + (size_t)(row0 + r) * HDIM + fs);
        float4 v[4];
#pragma unroll
        for (int i = 0; i < 4; ++i) v[i] = p[i];
        const float* vf = (const float*)v;
        unsigned* dst = (unsigned*)(sx + r * LDP + fs);
#pragma unroll
        for (int i = 0; i < 8; ++i) {
            unsigned lo = (unsigned)(unsigned short)f2bf(vf[2 * i]);
            unsigned hi = (unsigned)(unsigned short)f2bf(vf[2 * i + 1]);
            dst[i] = lo | (hi << 16);
        }
    }
    __syncthreads();

    const int w = t >> 6, l = t & 63;
    const int m16 = l & 15, quad = l >> 4;
    const int col = w * 16 + m16;

    short8 ones;
#pragma unroll
    for (int j = 0; j < 8; ++j) ones[j] = (short)0x3F80;  // bf16 1.0

    short8 wf[4];
#pragma unroll
    for (int q = 0; q < 4; ++q)
        wf[q] = *(const short8*)(pwE + (((q * 4 + quad) * 128 + col) << 3));

    f32x4 acc[4] = {}, rsum[4] = {};
#pragma unroll
    for (int q = 0; q < 4; ++q)
#pragma unroll
        for (int mt = 0; mt < 4; ++mt) {
            short8 a = *(const short8*)(sx + (mt * 16 + m16) * LDP + q * 32 + quad * 8);
            acc[mt]  = __builtin_amdgcn_mfma_f32_16x16x32_bf16(a, wf[q], acc[mt], 0, 0, 0);
            rsum[mt] = __builtin_amdgcn_mfma_f32_16x16x32_bf16(a, ones,  rsum[mt], 0, 0, 0);
        }

#pragma unroll
    for (int mt = 0; mt < 4; ++mt)
#pragma unroll
        for (int r = 0; r < 4; ++r) {
            const int rr = row0 + mt * 16 + quad * 4 + r;
            const float v = acc[mt][r] / rsum[mt][r];
            h0[(size_t)rr * HDIM + col] = __float2bfloat16(v);
            h8[(size_t)rr * HDIM + col] = f2fp8(v * H8SCALE);
        }
}

// ---------------- GCN layer: h_out = relu(NG@W + H@B) ----------------
// r11 structure (LBM=32, 256 thr, 4 blocks/CU, batch-XCD swizzle); gather
// now reads the fp8 mirror: one uint4 per neighbor per lane covers the
// whole 128B row -> single phase, half the L2 requests/bytes of bf16.
__global__ __launch_bounds__(256, 4) void layer_gemm(const bf16* __restrict__ h_in,
                                                     const unsigned char* __restrict__ h8_in,
                                                     const int* __restrict__ nidx,
                                                     const int* __restrict__ vlen,
                                                     const short* __restrict__ pwW,
                                                     const short* __restrict__ pwB,
                                                     bf16* __restrict__ h_out,
                                                     unsigned char* __restrict__ h8_out) {
    __shared__ int   sidx[LBM * KNBR];   // 4 KB
    __shared__ short sng[LBM * LDP];     // 8.7 KB
    __shared__ short sh[LBM * LDP];      // 8.7 KB

    const int slot = blockIdx.x & 7;
    const int half = slot >> 2;
    const int idx  = (blockIdx.x >> 3) * 4 + (slot & 3);
    if (idx >= LTPH) return;
    const int tile = half * LTPH + idx;

    const int t = threadIdx.x;
    const int row0 = tile * LBM;

    ((int4*)sidx)[t] = ((const int4*)(nidx + (size_t)row0 * KNBR))[t];
    {
        const int r = t >> 3, fs = (t & 7) * 16;
        const uint4* p = (const uint4*)(h_in + (size_t)(row0 + r) * HDIM + fs);
        uint4 a = p[0], b = p[1];
        uint4* d = (uint4*)(sh + r * LDP + fs);
        d[0] = a; d[1] = b;
    }
    __syncthreads();

    // ---- gather: 8 threads/node, 16 fp8 features each, single phase ----
    {
        const int node = t >> 3;
        const int fs16 = (t & 7) * 16;              // feature & byte offset
        const int g = row0 + node;
        const unsigned char* hb8 = h8_in + (size_t)((g >= NB) ? NB : 0) * HDIM;
        const int* ip = sidx + node * KNBR;
        int vl = vlen[g]; if (vl == 0) vl = 1;
        const float sc = H8INV / (float)vl;

        float acc[16];
#pragma unroll
        for (int i = 0; i < 16; ++i) acc[i] = 0.0f;
#pragma unroll 4
        for (int k = 0; k < KNBR; ++k) {
            const uint4 u = *(const uint4*)(hb8 + (size_t)ip[k] * HDIM + fs16);
            f32x2 p;
            p = __builtin_amdgcn_cvt_pk_f32_fp8(u.x, false); acc[0] += p.x;  acc[1] += p.y;
            p = __builtin_amdgcn_cvt_pk_f32_fp8(u.x, true);  acc[2] += p.x;  acc[3] += p.y;
            p = __builtin_amdgcn_cvt_pk_f32_fp8(u.y, false); acc[4] += p.x;  acc[5] += p.y;
            p = __builtin_amdgcn_cvt_pk_f32_fp8(u.y, true);  acc[6] += p.x;  acc[7] += p.y;
            p = __builtin_amdgcn_cvt_pk_f32_fp8(u.z, false); acc[8] += p.x;  acc[9] += p.y;
            p = __builtin_amdgcn_cvt_pk_f32_fp8(u.z, true);  acc[10] += p.x; acc[11] += p.y;
            p = __builtin_amdgcn_cvt_pk_f32_fp8(u.w, false); acc[12] += p.x; acc[13] += p.y;
            p = __builtin_amdgcn_cvt_pk_f32_fp8(u.w, true);  acc[14] += p.x; acc[15] += p.y;
        }
        unsigned* dst = (unsigned*)(sng + node * LDP + fs16);
#pragma unroll
        for (int i = 0; i < 8; ++i) {
            unsigned lo = (unsigned)(unsigned short)f2bf(acc[2 * i] * sc);
            unsigned hi = (unsigned)(unsigned short)f2bf(acc[2 * i + 1] * sc);
            dst[i] = lo | (hi << 16);
        }
    }
    __syncthreads();

    // ---- MFMA: acc = NG@W + H@B (wave w covers cols w*32..w*32+31) ----
    const int w = t >> 6, l = t & 63;
    const int m16 = l & 15, quad = l >> 4;
    const int ncol0 = w * 32;

    short8 wfW[2][4], wfB[2][4];
#pragma unroll
    for (int nt = 0; nt < 2; ++nt) {
        const int col = ncol0 + nt * 16 + m16;
#pragma unroll
        for (int q = 0; q < 4; ++q) {
            const int off = ((q * 4 + quad) * 128 + col) << 3;
            wfW[nt][q] = *(const short8*)(pwW + off);
            wfB[nt][q] = *(const short8*)(pwB + off);
        }
    }

    f32x4 acc[2][2] = {};
#pragma unroll
    for (int q = 0; q < 4; ++q)
#pragma unroll
        for (int mt = 0; mt < 2; ++mt) {
            short8 aN = *(const short8*)(sng + (mt * 16 + m16) * LDP + q * 32 + quad * 8);
            short8 aH = *(const short8*)(sh  + (mt * 16 + m16) * LDP + q * 32 + quad * 8);
#pragma unroll
            for (int nt = 0; nt < 2; ++nt) {
                acc[mt][nt] = __builtin_amdgcn_mfma_f32_16x16x32_bf16(aN, wfW[nt][q], acc[mt][nt], 0, 0, 0);
                acc[mt][nt] = __builtin_amdgcn_mfma_f32_16x16x32_bf16(aH, wfB[nt][q], acc[mt][nt], 0, 0, 0);
            }
        }

#pragma unroll
    for (int mt = 0; mt < 2; ++mt)
#pragma unroll
        for (int nt = 0; nt < 2; ++nt)
#pragma unroll
            for (int r = 0; r < 4; ++r) {
                const int rr = row0 + mt * 16 + quad * 4 + r;
                const int cc = ncol0 + nt * 16 + m16;
                const float v = fmaxf(acc[mt][nt][r], 0.0f);
                h_out[(size_t)rr * HDIM + cc] = __float2bfloat16(v);
                h8_out[(size_t)rr * HDIM + cc] = f2fp8(v * H8SCALE);
            }
}

// ---------------- classifier: softmax(relu(h@W1+b1)@W2 + b2) ----------------
__global__ __launch_bounds__(512, 4) void cls_gemm(const bf16* __restrict__ h,
                                                   const short* __restrict__ pwW1,
                                                   const float* __restrict__ b1,
                                                   const short* __restrict__ pwW2,
                                                   const float* __restrict__ b2,
                                                   float* __restrict__ out) {
    __shared__ short sh[BM * LDP];
    __shared__ short sz[BM * LDP];
    __shared__ float lg[BM * 48];
    const int t = threadIdx.x;
    const int row0 = blockIdx.x * BM;

    {
        const int r = t >> 3, fs = (t & 7) * 16;
        const uint4* p = (const uint4*)(h + (size_t)(row0 + r) * HDIM + fs);
        uint4 a = p[0], b = p[1];
        uint4* d = (uint4*)(sh + r * LDP + fs);
        d[0] = a; d[1] = b;
    }
    __syncthreads();

    const int w = t >> 6, l = t & 63;
    const int m16 = l & 15, quad = l >> 4;
    const int col = w * 16 + m16;

    // ---- stage 1: z = relu(h @ W1 + b1) -> LDS ----
    {
        short8 wf[4];
#pragma unroll
        for (int q = 0; q < 4; ++q)
            wf[q] = *(const short8*)(pwW1 + (((q * 4 + quad) * 128 + col) << 3));
        f32x4 acc[4] = {};
#pragma unroll
        for (int q = 0; q < 4; ++q)
#pragma unroll
            for (int mt = 0; mt < 4; ++mt) {
                short8 a = *(const short8*)(sh + (mt * 16 + m16) * LDP + q * 32 + quad * 8);
                acc[mt] = __builtin_amdgcn_mfma_f32_16x16x32_bf16(a, wf[q], acc[mt], 0, 0, 0);
            }
        const float bias = b1[col];
#pragma unroll
        for (int mt = 0; mt < 4; ++mt)
#pragma unroll
            for (int r = 0; r < 4; ++r)
                sz[(mt * 16 + quad * 4 + r) * LDP + col] = f2bf(fmaxf(acc[mt][r] + bias, 0.0f));
    }
    __syncthreads();

    // ---- stage 2: logits = z @ W2 + b2 (waves 0..2 cover 40 cols) ----
    if (w < 3) {
        const bool valid = (col < NCLS);
        short8 wf[4];
#pragma unroll
        for (int q = 0; q < 4; ++q) {
            if (valid) wf[q] = *(const short8*)(pwW2 + (((q * 4 + quad) * NCLS + col) << 3));
            else {
#pragma unroll
                for (int j = 0; j < 8; ++j) wf[q][j] = 0;
            }
        }
        f32x4 acc[4] = {};
#pragma unroll
        for (int q = 0; q < 4; ++q)
#pragma unroll
            for (int mt = 0; mt < 4; ++mt) {
                short8 a = *(const short8*)(sz + (mt * 16 + m16) * LDP + q * 32 + quad * 8);
                acc[mt] = __builtin_amdgcn_mfma_f32_16x16x32_bf16(a, wf[q], acc[mt], 0, 0, 0);
            }
        if (valid) {
            const float bias = b2[col];
#pragma unroll
            for (int mt = 0; mt < 4; ++mt)
#pragma unroll
                for (int r = 0; r < 4; ++r)
                    lg[(mt * 16 + quad * 4 + r) * 48 + col] = acc[mt][r] + bias;
        }
    }
    __syncthreads();

    // ---- softmax per row ----
    if (t < BM) {
        float* row = lg + t * 48;
        float m = row[0];
        for (int c = 1; c < NCLS; ++c) m = fmaxf(m, row[c]);
        float s = 0.0f;
        for (int c = 0; c < NCLS; ++c) { float e = expf(row[c] - m); row[c] = e; s += e; }
        const float inv = 1.0f / s;
        for (int c = 0; c < NCLS; ++c) row[c] *= inv;
    }
    __syncthreads();

    for (int i = t; i < BM * NCLS; i += 512) {
        const int r = i / NCLS, c = i - r * NCLS;
        out[(size_t)row0 * NCLS + i] = lg[r * 48 + c];
    }
}

extern "C" void kernel_launch(void* const* d_in, const int* in_sizes, int n_in,
                              void* d_out, int out_size, void* d_ws, size_t ws_size,
                              hipStream_t stream) {
    const float* x    = (const float*)d_in[0];
    const int*  nidx  = (const int*)  d_in[1];
    const int*  vlen  = (const int*)  d_in[2];
    const float* Wemb = (const float*)d_in[3];
    const float* gW   = (const float*)d_in[4];
    const float* gB   = (const float*)d_in[5];
    const float* W1   = (const float*)d_in[6];
    const float* b1   = (const float*)d_in[7];
    const float* W2   = (const float*)d_in[8];
    const float* b2   = (const float*)d_in[9];
    float* out = (float*)d_out;

    const int nodes = BATCH * NB;           // 40000
    bf16* h0 = (bf16*)d_ws;                                  // 10.24 MB
    bf16* h1 = h0 + (size_t)nodes * HDIM;                    // 10.24 MB
    unsigned char* h8a = (unsigned char*)(h1 + (size_t)nodes * HDIM);  // 5.12 MB
    unsigned char* h8b = h8a + (size_t)nodes * HDIM;                   // 5.12 MB
    short* pw = (short*)(h8b + (size_t)nodes * HDIM);        // 272 KB packed weights
    const short* pwE  = pw;
    const short* pwW1 = pw + 7 * 16384;
    const short* pwW2 = pw + 8 * 16384;

    pack_weights<<<(8 * 16384 + 128 * NCLS + 255) / 256, 256, 0, stream>>>(Wemb, gW, gB, W1, W2, pw);
    embed_gemm<<<NTILES, 512, 0, stream>>>(x, pwE, h0, h8a);

    for (int lyr = 0; lyr < NLAYER; ++lyr) {
        layer_gemm<<<LGRID, 256, 0, stream>>>(h0, h8a, nidx, vlen,
                                              pw + (size_t)(1 + lyr) * 16384,
                                              pw + (size_t)(4 + lyr) * 16384,
                                              h1, h8b);
        bf16* tmp = h0; h0 = h1; h1 = tmp;
        unsigned char* t8 = h8a; h8a = h8b; h8b = t8;
    }

    cls_gemm<<<NTILES, 512, 0, stream>>>(h0, pwW1, b1, pwW2, b2, out);
}

// Round 13
// 169.285 us; speedup vs baseline: 1.0258x; 1.0258x over previous
//
#include <hip/hip_runtime.h>
#include <hip/hip_bf16.h>

typedef __hip_bfloat16 bf16;
typedef __attribute__((ext_vector_type(8))) short short8;
typedef __attribute__((ext_vector_type(4))) float f32x4;

#define NB    20000
#define BATCH 2
#define HDIM  128
#define KNBR  32
#define NCLS  40
#define NLAYER 3
#define BM    64          // rows per tile: embed/cls kernels
#define LBM   32          // rows per tile: layer kernel
#define LDP   136         // padded LDS row stride (bf16 elems): 272 B, 16B-aligned
#define NTILES 625        // 64-row tiles over 40000 nodes (embed/cls)
#define LTPH   625        // 32-row layer tiles per batch half (20000/32, exact)
#define LGRID  1256       // 8*157, batch-XCD swizzled with guards

__device__ __forceinline__ short f2bf(float v) {
    return __builtin_bit_cast(short, __float2bfloat16(v));
}
__device__ __forceinline__ float blo(unsigned u) { return __builtin_bit_cast(float, u << 16); }
__device__ __forceinline__ float bhi(unsigned u) { return __builtin_bit_cast(float, u & 0xffff0000u); }

// ---------------- weight pre-pack: f32 [K][N] -> bf16 fragment layout ----------------
__global__ void pack_weights(const float* __restrict__ Wemb, const float* __restrict__ gW,
                             const float* __restrict__ gB, const float* __restrict__ W1,
                             const float* __restrict__ W2, short* __restrict__ pw) {
    const int idx = blockIdx.x * 256 + threadIdx.x;
    if (idx < 8 * 16384) {
        const int m = idx >> 14, e = idx & 16383;
        const float* src = (m == 0) ? Wemb
                         : (m <= 3) ? gW + (size_t)(m - 1) * 16384
                         : (m <= 6) ? gB + (size_t)(m - 4) * 16384
                         : W1;
        const int k = e >> 7, n = e & 127;
        pw[m * 16384 + (((k >> 3) * 128 + n) << 3) + (k & 7)] = f2bf(src[e]);
    } else {
        const int e = idx - 8 * 16384;
        if (e < 128 * NCLS) {
            const int k = e / NCLS, n = e - k * NCLS;
            pw[8 * 16384 + ((k >> 3) * NCLS + n) * 8 + (k & 7)] = f2bf(W2[e]);
        }
    }
}

// ---------------- embed: h0 = (x @ Wemb) / rowsum(x), rowsum via ones-MFMA ----------------
__global__ __launch_bounds__(512, 4) void embed_gemm(const float* __restrict__ x,
                                                     const short* __restrict__ pwE,
                                                     bf16* __restrict__ h0) {
    __shared__ short sx[BM * LDP];
    const int t = threadIdx.x;
    const int row0 = blockIdx.x * BM;

    {
        const int r = t >> 3, fs = (t & 7) * 16;
        const float4* p = (const float4*)(x + (size_t)(row0 + r) * HDIM + fs);
        float4 v[4];
#pragma unroll
        for (int i = 0; i < 4; ++i) v[i] = p[i];
        const float* vf = (const float*)v;
        unsigned* dst = (unsigned*)(sx + r * LDP + fs);
#pragma unroll
        for (int i = 0; i < 8; ++i) {
            unsigned lo = (unsigned)(unsigned short)f2bf(vf[2 * i]);
            unsigned hi = (unsigned)(unsigned short)f2bf(vf[2 * i + 1]);
            dst[i] = lo | (hi << 16);
        }
    }
    __syncthreads();

    const int w = t >> 6, l = t & 63;
    const int m16 = l & 15, quad = l >> 4;
    const int col = w * 16 + m16;

    short8 ones;
#pragma unroll
    for (int j = 0; j < 8; ++j) ones[j] = (short)0x3F80;  // bf16 1.0

    short8 wf[4];
#pragma unroll
    for (int q = 0; q < 4; ++q)
        wf[q] = *(const short8*)(pwE + (((q * 4 + quad) * 128 + col) << 3));

    f32x4 acc[4] = {}, rsum[4] = {};
#pragma unroll
    for (int q = 0; q < 4; ++q)
#pragma unroll
        for (int mt = 0; mt < 4; ++mt) {
            short8 a = *(const short8*)(sx + (mt * 16 + m16) * LDP + q * 32 + quad * 8);
            acc[mt]  = __builtin_amdgcn_mfma_f32_16x16x32_bf16(a, wf[q], acc[mt], 0, 0, 0);
            rsum[mt] = __builtin_amdgcn_mfma_f32_16x16x32_bf16(a, ones,  rsum[mt], 0, 0, 0);
        }

#pragma unroll
    for (int mt = 0; mt < 4; ++mt)
#pragma unroll
        for (int r = 0; r < 4; ++r) {
            const int rr = row0 + mt * 16 + quad * 4 + r;
            h0[(size_t)rr * HDIM + col] = __float2bfloat16(acc[mt][r] / rsum[mt][r]);
        }
}

// ---------------- GCN layer: h_out = relu(NG@W + H@B) ----------------
// r11 structure; ONE lever: (256,6) -> 6 blocks/CU (24 waves) for more
// outstanding gather misses.  To fit the 85-VGPR cap without hot-loop
// spills, MFMA weight frags load per-q (16 live regs, L1-hot broadcast).
__global__ __launch_bounds__(256, 6) void layer_gemm(const bf16* __restrict__ h_in,
                                                     const int* __restrict__ nidx,
                                                     const int* __restrict__ vlen,
                                                     const short* __restrict__ pwW,
                                                     const short* __restrict__ pwB,
                                                     bf16* __restrict__ h_out) {
    __shared__ int   sidx[LBM * KNBR];   // 4 KB
    __shared__ short sng[LBM * LDP];     // 8.7 KB
    __shared__ short sh[LBM * LDP];      // 8.7 KB

    const int slot = blockIdx.x & 7;
    const int half = slot >> 2;
    const int idx  = (blockIdx.x >> 3) * 4 + (slot & 3);
    if (idx >= LTPH) return;
    const int tile = half * LTPH + idx;

    const int t = threadIdx.x;
    const int row0 = tile * LBM;

    ((int4*)sidx)[t] = ((const int4*)(nidx + (size_t)row0 * KNBR))[t];
    {
        const int r = t >> 3, fs = (t & 7) * 16;
        const uint4* p = (const uint4*)(h_in + (size_t)(row0 + r) * HDIM + fs);
        uint4 a = p[0], b = p[1];
        uint4* d = (uint4*)(sh + r * LDP + fs);
        d[0] = a; d[1] = b;
    }
    __syncthreads();

    // ---- gather: 8 threads/node, 8 features, 2 phases (r11 inner loop) ----
    {
        const int node = t >> 3;
        const int fs8 = (t & 7) * 8;
        const int g = row0 + node;
        const bf16* hb = h_in + (size_t)((g >= NB) ? NB : 0) * HDIM;
        const int* ip = sidx + node * KNBR;
        int vl = vlen[g]; if (vl == 0) vl = 1;
        const float inv = 1.0f / (float)vl;

#pragma unroll
        for (int fh = 0; fh < 2; ++fh) {
            const int fs = fh * 64 + fs8;
            float acc[8];
#pragma unroll
            for (int i = 0; i < 8; ++i) acc[i] = 0.0f;
#pragma unroll 4
            for (int k = 0; k < KNBR; ++k) {
                const uint4 u = *(const uint4*)(hb + (size_t)ip[k] * HDIM + fs);
                acc[0] += blo(u.x); acc[1] += bhi(u.x);
                acc[2] += blo(u.y); acc[3] += bhi(u.y);
                acc[4] += blo(u.z); acc[5] += bhi(u.z);
                acc[6] += blo(u.w); acc[7] += bhi(u.w);
            }
            unsigned* dst = (unsigned*)(sng + node * LDP + fs);
#pragma unroll
            for (int i = 0; i < 4; ++i) {
                unsigned lo = (unsigned)(unsigned short)f2bf(acc[2 * i] * inv);
                unsigned hi = (unsigned)(unsigned short)f2bf(acc[2 * i + 1] * inv);
                dst[i] = lo | (hi << 16);
            }
            __syncthreads();   // phase alignment keeps L2 working set tight
        }
    }

    // ---- MFMA: acc = NG@W + H@B (wave w covers cols w*32..w*32+31) ----
    const int w = t >> 6, l = t & 63;
    const int m16 = l & 15, quad = l >> 4;
    const int ncol0 = w * 32;

    f32x4 acc[2][2] = {};
#pragma unroll
    for (int q = 0; q < 4; ++q) {
        short8 wfW[2], wfB[2];
#pragma unroll
        for (int nt = 0; nt < 2; ++nt) {
            const int off = ((q * 4 + quad) * 128 + ncol0 + nt * 16 + m16) << 3;
            wfW[nt] = *(const short8*)(pwW + off);
            wfB[nt] = *(const short8*)(pwB + off);
        }
#pragma unroll
        for (int mt = 0; mt < 2; ++mt) {
            short8 aN = *(const short8*)(sng + (mt * 16 + m16) * LDP + q * 32 + quad * 8);
            short8 aH = *(const short8*)(sh  + (mt * 16 + m16) * LDP + q * 32 + quad * 8);
#pragma unroll
            for (int nt = 0; nt < 2; ++nt) {
                acc[mt][nt] = __builtin_amdgcn_mfma_f32_16x16x32_bf16(aN, wfW[nt], acc[mt][nt], 0, 0, 0);
                acc[mt][nt] = __builtin_amdgcn_mfma_f32_16x16x32_bf16(aH, wfB[nt], acc[mt][nt], 0, 0, 0);
            }
        }
    }

#pragma unroll
    for (int mt = 0; mt < 2; ++mt)
#pragma unroll
        for (int nt = 0; nt < 2; ++nt)
#pragma unroll
            for (int r = 0; r < 4; ++r) {
                const int rr = row0 + mt * 16 + quad * 4 + r;
                const int cc = ncol0 + nt * 16 + m16;
                h_out[(size_t)rr * HDIM + cc] = __float2bfloat16(fmaxf(acc[mt][nt][r], 0.0f));
            }
}

// ---------------- classifier: softmax(relu(h@W1+b1)@W2 + b2) ----------------
__global__ __launch_bounds__(512, 4) void cls_gemm(const bf16* __restrict__ h,
                                                   const short* __restrict__ pwW1,
                                                   const float* __restrict__ b1,
                                                   const short* __restrict__ pwW2,
                                                   const float* __restrict__ b2,
                                                   float* __restrict__ out) {
    __shared__ short sh[BM * LDP];
    __shared__ short sz[BM * LDP];
    __shared__ float lg[BM * 48];
    const int t = threadIdx.x;
    const int row0 = blockIdx.x * BM;

    {
        const int r = t >> 3, fs = (t & 7) * 16;
        const uint4* p = (const uint4*)(h + (size_t)(row0 + r) * HDIM + fs);
        uint4 a = p[0], b = p[1];
        uint4* d = (uint4*)(sh + r * LDP + fs);
        d[0] = a; d[1] = b;
    }
    __syncthreads();

    const int w = t >> 6, l = t & 63;
    const int m16 = l & 15, quad = l >> 4;
    const int col = w * 16 + m16;

    // ---- stage 1: z = relu(h @ W1 + b1) -> LDS ----
    {
        short8 wf[4];
#pragma unroll
        for (int q = 0; q < 4; ++q)
            wf[q] = *(const short8*)(pwW1 + (((q * 4 + quad) * 128 + col) << 3));
        f32x4 acc[4] = {};
#pragma unroll
        for (int q = 0; q < 4; ++q)
#pragma unroll
            for (int mt = 0; mt < 4; ++mt) {
                short8 a = *(const short8*)(sh + (mt * 16 + m16) * LDP + q * 32 + quad * 8);
                acc[mt] = __builtin_amdgcn_mfma_f32_16x16x32_bf16(a, wf[q], acc[mt], 0, 0, 0);
            }
        const float bias = b1[col];
#pragma unroll
        for (int mt = 0; mt < 4; ++mt)
#pragma unroll
            for (int r = 0; r < 4; ++r)
                sz[(mt * 16 + quad * 4 + r) * LDP + col] = f2bf(fmaxf(acc[mt][r] + bias, 0.0f));
    }
    __syncthreads();

    // ---- stage 2: logits = z @ W2 + b2 (waves 0..2 cover 40 cols) ----
    if (w < 3) {
        const bool valid = (col < NCLS);
        short8 wf[4];
#pragma unroll
        for (int q = 0; q < 4; ++q) {
            if (valid) wf[q] = *(const short8*)(pwW2 + (((q * 4 + quad) * NCLS + col) << 3));
            else {
#pragma unroll
                for (int j = 0; j < 8; ++j) wf[q][j] = 0;
            }
        }
        f32x4 acc[4] = {};
#pragma unroll
        for (int q = 0; q < 4; ++q)
#pragma unroll
            for (int mt = 0; mt < 4; ++mt) {
                short8 a = *(const short8*)(sz + (mt * 16 + m16) * LDP + q * 32 + quad * 8);
                acc[mt] = __builtin_amdgcn_mfma_f32_16x16x32_bf16(a, wf[q], acc[mt], 0, 0, 0);
            }
        if (valid) {
            const float bias = b2[col];
#pragma unroll
            for (int mt = 0; mt < 4; ++mt)
#pragma unroll
                for (int r = 0; r < 4; ++r)
                    lg[(mt * 16 + quad * 4 + r) * 48 + col] = acc[mt][r] + bias;
        }
    }
    __syncthreads();

    // ---- softmax per row ----
    if (t < BM) {
        float* row = lg + t * 48;
        float m = row[0];
        for (int c = 1; c < NCLS; ++c) m = fmaxf(m, row[c]);
        float s = 0.0f;
        for (int c = 0; c < NCLS; ++c) { float e = expf(row[c] - m); row[c] = e; s += e; }
        const float inv = 1.0f / s;
        for (int c = 0; c < NCLS; ++c) row[c] *= inv;
    }
    __syncthreads();

    for (int i = t; i < BM * NCLS; i += 512) {
        const int r = i / NCLS, c = i - r * NCLS;
        out[(size_t)row0 * NCLS + i] = lg[r * 48 + c];
    }
}

extern "C" void kernel_launch(void* const* d_in, const int* in_sizes, int n_in,
                              void* d_out, int out_size, void* d_ws, size_t ws_size,
                              hipStream_t stream) {
    const float* x    = (const float*)d_in[0];
    const int*  nidx  = (const int*)  d_in[1];
    const int*  vlen  = (const int*)  d_in[2];
    const float* Wemb = (const float*)d_in[3];
    const float* gW   = (const float*)d_in[4];
    const float* gB   = (const float*)d_in[5];
    const float* W1   = (const float*)d_in[6];
    const float* b1   = (const float*)d_in[7];
    const float* W2   = (const float*)d_in[8];
    const float* b2   = (const float*)d_in[9];
    float* out = (float*)d_out;

    const int nodes = BATCH * NB;           // 40000
    bf16* h0 = (bf16*)d_ws;
    bf16* h1 = h0 + (size_t)nodes * HDIM;
    short* pw = (short*)(h1 + (size_t)nodes * HDIM);   // 272 KB packed weights
    const short* pwE  = pw;
    const short* pwW1 = pw + 7 * 16384;
    const short* pwW2 = pw + 8 * 16384;

    pack_weights<<<(8 * 16384 + 128 * NCLS + 255) / 256, 256, 0, stream>>>(Wemb, gW, gB, W1, W2, pw);
    embed_gemm<<<NTILES, 512, 0, stream>>>(x, pwE, h0);

    for (int lyr = 0; lyr < NLAYER; ++lyr) {
        layer_gemm<<<LGRID, 256, 0, stream>>>(h0, nidx, vlen,
                                              pw + (size_t)(1 + lyr) * 16384,
                                              pw + (size_t)(4 + lyr) * 16384,
                                              h1);
        bf16* tmp = h0; h0 = h1; h1 = tmp;
    }

    cls_gemm<<<NTILES, 512, 0, stream>>>(h0, pwW1, b1, pwW2, b2, out);
}

// Round 15
// 161.336 us; speedup vs baseline: 1.0764x; 1.0493x over previous
//
#include <hip/hip_runtime.h>
#include <hip/hip_bf16.h>

typedef __hip_bfloat16 bf16;
typedef __attribute__((ext_vector_type(8))) short short8;
typedef __attribute__((ext_vector_type(4))) float f32x4;

#define NB    20000
#define HDIM  128
#define KNBR  32
#define NCLS  40
#define BM    64          // rows per tile: embed
#define LBM   32          // rows per tile: layer/cls
#define LDP   136         // padded LDS row stride (bf16 elems)
#define NTILES 625        // 64-row embed tiles over 40000 nodes
#define LTPH   625        // 32-row layer tiles per batch half (exact)
#define LGRID  1256       // 8*157, batch-XCD swizzled with guards
#define PACKN  (8*16384 + 128*NCLS)   // packed weight element count
#define EGRID  (NTILES + 64)          // embed tiles + 64 pack blocks

__device__ __forceinline__ short f2bf(float v) {
    return __builtin_bit_cast(short, __float2bfloat16(v));
}
__device__ __forceinline__ float blo(unsigned u) { return __builtin_bit_cast(float, u << 16); }
__device__ __forceinline__ float bhi(unsigned u) { return __builtin_bit_cast(float, u & 0xffff0000u); }

// ---------------- dispatch 1: embed (blocks 0..624) + weight pack (blocks 625..688) ----------------
// embed reads f32 Wemb directly (no dependency on pack); pack finishes
// before layer 1 by stream ordering.
__global__ __launch_bounds__(512, 4) void embed_pack(const float* __restrict__ x,
                                                     const float* __restrict__ Wemb,
                                                     const float* __restrict__ gW,
                                                     const float* __restrict__ gB,
                                                     const float* __restrict__ W1,
                                                     const float* __restrict__ W2,
                                                     bf16* __restrict__ h0,
                                                     short* __restrict__ pw) {
    const int t = threadIdx.x;

    if (blockIdx.x >= NTILES) {
        // ---- pack: f32 [K][N] -> bf16 fragment layout, grid-stride ----
        for (int idx = (blockIdx.x - NTILES) * 512 + t; idx < PACKN; idx += 64 * 512) {
            if (idx < 8 * 16384) {
                const int m = idx >> 14, e = idx & 16383;
                const float* src = (m == 0) ? Wemb
                                 : (m <= 3) ? gW + (size_t)(m - 1) * 16384
                                 : (m <= 6) ? gB + (size_t)(m - 4) * 16384
                                 : W1;
                const int k = e >> 7, n = e & 127;
                pw[m * 16384 + (((k >> 3) * 128 + n) << 3) + (k & 7)] = f2bf(src[e]);
            } else {
                const int e = idx - 8 * 16384;
                const int k = e / NCLS, n = e - k * NCLS;
                pw[8 * 16384 + ((k >> 3) * NCLS + n) * 8 + (k & 7)] = f2bf(W2[e]);
            }
        }
        return;
    }

    // ---- embed: h0 = (x @ Wemb) / rowsum(x), rowsum via ones-MFMA ----
    __shared__ short sx[BM * LDP];
    const int row0 = blockIdx.x * BM;
    {
        const int r = t >> 3, fs = (t & 7) * 16;
        const float4* p = (const float4*)(x + (size_t)(row0 + r) * HDIM + fs);
        float4 v[4];
#pragma unroll
        for (int i = 0; i < 4; ++i) v[i] = p[i];
        const float* vf = (const float*)v;
        unsigned* dst = (unsigned*)(sx + r * LDP + fs);
#pragma unroll
        for (int i = 0; i < 8; ++i) {
            unsigned lo = (unsigned)(unsigned short)f2bf(vf[2 * i]);
            unsigned hi = (unsigned)(unsigned short)f2bf(vf[2 * i + 1]);
            dst[i] = lo | (hi << 16);
        }
    }
    __syncthreads();

    const int w = t >> 6, l = t & 63;
    const int m16 = l & 15, quad = l >> 4;
    const int col = w * 16 + m16;

    short8 ones;
#pragma unroll
    for (int j = 0; j < 8; ++j) ones[j] = (short)0x3F80;  // bf16 1.0

    short8 wf[4];
#pragma unroll
    for (int q = 0; q < 4; ++q) {
        const int kb = q * 32 + quad * 8;
#pragma unroll
        for (int j = 0; j < 8; ++j)
            wf[q][j] = f2bf(Wemb[(kb + j) * HDIM + col]);   // f32 direct, no pack dep
    }

    f32x4 acc[4] = {}, rsum[4] = {};
#pragma unroll
    for (int q = 0; q < 4; ++q)
#pragma unroll
        for (int mt = 0; mt < 4; ++mt) {
            short8 a = *(const short8*)(sx + (mt * 16 + m16) * LDP + q * 32 + quad * 8);
            acc[mt]  = __builtin_amdgcn_mfma_f32_16x16x32_bf16(a, wf[q], acc[mt], 0, 0, 0);
            rsum[mt] = __builtin_amdgcn_mfma_f32_16x16x32_bf16(a, ones,  rsum[mt], 0, 0, 0);
        }

#pragma unroll
    for (int mt = 0; mt < 4; ++mt)
#pragma unroll
        for (int r = 0; r < 4; ++r) {
            const int rr = row0 + mt * 16 + quad * 4 + r;
            h0[(size_t)rr * HDIM + col] = __float2bfloat16(acc[mt][r] / rsum[mt][r]);
        }
}

// ---------------- dispatches 2,3: GCN layer (r13 form, byte-identical) ----------------
__global__ __launch_bounds__(256, 6) void layer_gemm(const bf16* __restrict__ h_in,
                                                     const int* __restrict__ nidx,
                                                     const int* __restrict__ vlen,
                                                     const short* __restrict__ pwW,
                                                     const short* __restrict__ pwB,
                                                     bf16* __restrict__ h_out) {
    __shared__ int   sidx[LBM * KNBR];
    __shared__ short sng[LBM * LDP];
    __shared__ short sh[LBM * LDP];

    const int slot = blockIdx.x & 7;
    const int half = slot >> 2;
    const int idx  = (blockIdx.x >> 3) * 4 + (slot & 3);
    if (idx >= LTPH) return;
    const int tile = half * LTPH + idx;

    const int t = threadIdx.x;
    const int row0 = tile * LBM;

    ((int4*)sidx)[t] = ((const int4*)(nidx + (size_t)row0 * KNBR))[t];
    {
        const int r = t >> 3, fs = (t & 7) * 16;
        const uint4* p = (const uint4*)(h_in + (size_t)(row0 + r) * HDIM + fs);
        uint4 a = p[0], b = p[1];
        uint4* d = (uint4*)(sh + r * LDP + fs);
        d[0] = a; d[1] = b;
    }
    __syncthreads();

    {
        const int node = t >> 3;
        const int fs8 = (t & 7) * 8;
        const int g = row0 + node;
        const bf16* hb = h_in + (size_t)((g >= NB) ? NB : 0) * HDIM;
        const int* ip = sidx + node * KNBR;
        int vl = vlen[g]; if (vl == 0) vl = 1;
        const float inv = 1.0f / (float)vl;

#pragma unroll
        for (int fh = 0; fh < 2; ++fh) {
            const int fs = fh * 64 + fs8;
            float acc[8];
#pragma unroll
            for (int i = 0; i < 8; ++i) acc[i] = 0.0f;
#pragma unroll 4
            for (int k = 0; k < KNBR; ++k) {
                const uint4 u = *(const uint4*)(hb + (size_t)ip[k] * HDIM + fs);
                acc[0] += blo(u.x); acc[1] += bhi(u.x);
                acc[2] += blo(u.y); acc[3] += bhi(u.y);
                acc[4] += blo(u.z); acc[5] += bhi(u.z);
                acc[6] += blo(u.w); acc[7] += bhi(u.w);
            }
            unsigned* dst = (unsigned*)(sng + node * LDP + fs);
#pragma unroll
            for (int i = 0; i < 4; ++i) {
                unsigned lo = (unsigned)(unsigned short)f2bf(acc[2 * i] * inv);
                unsigned hi = (unsigned)(unsigned short)f2bf(acc[2 * i + 1] * inv);
                dst[i] = lo | (hi << 16);
            }
            __syncthreads();
        }
    }

    const int w = t >> 6, l = t & 63;
    const int m16 = l & 15, quad = l >> 4;
    const int ncol0 = w * 32;

    f32x4 acc[2][2] = {};
#pragma unroll
    for (int q = 0; q < 4; ++q) {
        short8 wfW[2], wfB[2];
#pragma unroll
        for (int nt = 0; nt < 2; ++nt) {
            const int off = ((q * 4 + quad) * 128 + ncol0 + nt * 16 + m16) << 3;
            wfW[nt] = *(const short8*)(pwW + off);
            wfB[nt] = *(const short8*)(pwB + off);
        }
#pragma unroll
        for (int mt = 0; mt < 2; ++mt) {
            short8 aN = *(const short8*)(sng + (mt * 16 + m16) * LDP + q * 32 + quad * 8);
            short8 aH = *(const short8*)(sh  + (mt * 16 + m16) * LDP + q * 32 + quad * 8);
#pragma unroll
            for (int nt = 0; nt < 2; ++nt) {
                acc[mt][nt] = __builtin_amdgcn_mfma_f32_16x16x32_bf16(aN, wfW[nt], acc[mt][nt], 0, 0, 0);
                acc[mt][nt] = __builtin_amdgcn_mfma_f32_16x16x32_bf16(aH, wfB[nt], acc[mt][nt], 0, 0, 0);
            }
        }
    }

#pragma unroll
    for (int mt = 0; mt < 2; ++mt)
#pragma unroll
        for (int nt = 0; nt < 2; ++nt)
#pragma unroll
            for (int r = 0; r < 4; ++r) {
                const int rr = row0 + mt * 16 + quad * 4 + r;
                const int cc = ncol0 + nt * 16 + m16;
                h_out[(size_t)rr * HDIM + cc] = __float2bfloat16(fmaxf(acc[mt][nt][r], 0.0f));
            }
}

// ---------------- dispatch 4: layer 3 + fused classifier ----------------
// Layer body identical to layer_gemm, but h3 is rounded to bf16 into LDS
// (bit-identical to the global round-trip) and cls runs in-block: tile T's
// cls needs only tile T's rows (no gather in cls).
__global__ __launch_bounds__(256, 4) void layer3_cls(const bf16* __restrict__ h_in,
                                                     const int* __restrict__ nidx,
                                                     const int* __restrict__ vlen,
                                                     const short* __restrict__ pwW,
                                                     const short* __restrict__ pwB,
                                                     const short* __restrict__ pwW1,
                                                     const float* __restrict__ b1,
                                                     const short* __restrict__ pwW2,
                                                     const float* __restrict__ b2,
                                                     float* __restrict__ out) {
    __shared__ int   sidx[LBM * KNBR];   // 4 KB
    __shared__ short sng[LBM * LDP];     // 8.7 KB (gather NG, then z-tile)
    __shared__ short sh[LBM * LDP];      // 8.7 KB (h_in tile, then h3 tile)
    __shared__ float lg[LBM * 48];       // 6 KB (logits)

    const int slot = blockIdx.x & 7;
    const int half = slot >> 2;
    const int idx  = (blockIdx.x >> 3) * 4 + (slot & 3);
    if (idx >= LTPH) return;
    const int tile = half * LTPH + idx;

    const int t = threadIdx.x;
    const int row0 = tile * LBM;

    ((int4*)sidx)[t] = ((const int4*)(nidx + (size_t)row0 * KNBR))[t];
    {
        const int r = t >> 3, fs = (t & 7) * 16;
        const uint4* p = (const uint4*)(h_in + (size_t)(row0 + r) * HDIM + fs);
        uint4 a = p[0], b = p[1];
        uint4* d = (uint4*)(sh + r * LDP + fs);
        d[0] = a; d[1] = b;
    }
    __syncthreads();

    {
        const int node = t >> 3;
        const int fs8 = (t & 7) * 8;
        const int g = row0 + node;
        const bf16* hb = h_in + (size_t)((g >= NB) ? NB : 0) * HDIM;
        const int* ip = sidx + node * KNBR;
        int vl = vlen[g]; if (vl == 0) vl = 1;
        const float inv = 1.0f / (float)vl;

#pragma unroll
        for (int fh = 0; fh < 2; ++fh) {
            const int fs = fh * 64 + fs8;
            float acc[8];
#pragma unroll
            for (int i = 0; i < 8; ++i) acc[i] = 0.0f;
#pragma unroll 4
            for (int k = 0; k < KNBR; ++k) {
                const uint4 u = *(const uint4*)(hb + (size_t)ip[k] * HDIM + fs);
                acc[0] += blo(u.x); acc[1] += bhi(u.x);
                acc[2] += blo(u.y); acc[3] += bhi(u.y);
                acc[4] += blo(u.z); acc[5] += bhi(u.z);
                acc[6] += blo(u.w); acc[7] += bhi(u.w);
            }
            unsigned* dst = (unsigned*)(sng + node * LDP + fs);
#pragma unroll
            for (int i = 0; i < 4; ++i) {
                unsigned lo = (unsigned)(unsigned short)f2bf(acc[2 * i] * inv);
                unsigned hi = (unsigned)(unsigned short)f2bf(acc[2 * i + 1] * inv);
                dst[i] = lo | (hi << 16);
            }
            __syncthreads();
        }
    }

    const int w = t >> 6, l = t & 63;
    const int m16 = l & 15, quad = l >> 4;
    const int ncol0 = w * 32;

    f32x4 acc[2][2] = {};
#pragma unroll
    for (int q = 0; q < 4; ++q) {
        short8 wfW[2], wfB[2];
#pragma unroll
        for (int nt = 0; nt < 2; ++nt) {
            const int off = ((q * 4 + quad) * 128 + ncol0 + nt * 16 + m16) << 3;
            wfW[nt] = *(const short8*)(pwW + off);
            wfB[nt] = *(const short8*)(pwB + off);
        }
#pragma unroll
        for (int mt = 0; mt < 2; ++mt) {
            short8 aN = *(const short8*)(sng + (mt * 16 + m16) * LDP + q * 32 + quad * 8);
            short8 aH = *(const short8*)(sh  + (mt * 16 + m16) * LDP + q * 32 + quad * 8);
#pragma unroll
            for (int nt = 0; nt < 2; ++nt) {
                acc[mt][nt] = __builtin_amdgcn_mfma_f32_16x16x32_bf16(aN, wfW[nt], acc[mt][nt], 0, 0, 0);
                acc[mt][nt] = __builtin_amdgcn_mfma_f32_16x16x32_bf16(aH, wfB[nt], acc[mt][nt], 0, 0, 0);
            }
        }
    }
    __syncthreads();   // all waves done reading sh before h3 overwrites it

    // h3 = relu(...) rounded to bf16 -> sh (replaces global round-trip)
#pragma unroll
    for (int mt = 0; mt < 2; ++mt)
#pragma unroll
        for (int nt = 0; nt < 2; ++nt)
#pragma unroll
            for (int r = 0; r < 4; ++r) {
                const int lr = mt * 16 + quad * 4 + r;
                const int cc = ncol0 + nt * 16 + m16;
                sh[lr * LDP + cc] = f2bf(fmaxf(acc[mt][nt][r], 0.0f));
            }
    __syncthreads();

    // ---- cls stage 1: z = relu(h3 @ W1 + b1) -> sng ----
    {
        f32x4 zacc[2][2] = {};
#pragma unroll
        for (int q = 0; q < 4; ++q) {
            short8 wf[2];
#pragma unroll
            for (int nt = 0; nt < 2; ++nt)
                wf[nt] = *(const short8*)(pwW1 + (((q * 4 + quad) * 128 + ncol0 + nt * 16 + m16) << 3));
#pragma unroll
            for (int mt = 0; mt < 2; ++mt) {
                short8 a = *(const short8*)(sh + (mt * 16 + m16) * LDP + q * 32 + quad * 8);
#pragma unroll
                for (int nt = 0; nt < 2; ++nt)
                    zacc[mt][nt] = __builtin_amdgcn_mfma_f32_16x16x32_bf16(a, wf[nt], zacc[mt][nt], 0, 0, 0);
            }
        }
        __syncthreads();   // done reading sng (gather buffer) -> reuse as z
#pragma unroll
        for (int nt = 0; nt < 2; ++nt) {
            const int cc = ncol0 + nt * 16 + m16;
            const float bias = b1[cc];
#pragma unroll
            for (int mt = 0; mt < 2; ++mt)
#pragma unroll
                for (int r = 0; r < 4; ++r)
                    sng[(mt * 16 + quad * 4 + r) * LDP + cc] = f2bf(fmaxf(zacc[mt][nt][r] + bias, 0.0f));
        }
    }
    __syncthreads();

    // ---- cls stage 2: logits = z @ W2 + b2 (waves 0..2 cover 40 cols) ----
    if (w < 3) {
        const int col = w * 16 + m16;
        const bool valid = (col < NCLS);
        f32x4 lacc[2] = {};
#pragma unroll
        for (int q = 0; q < 4; ++q) {
            short8 wf;
            if (valid) wf = *(const short8*)(pwW2 + (((q * 4 + quad) * NCLS + col) << 3));
            else {
#pragma unroll
                for (int j = 0; j < 8; ++j) wf[j] = 0;
            }
#pragma unroll
            for (int mt = 0; mt < 2; ++mt) {
                short8 a = *(const short8*)(sng + (mt * 16 + m16) * LDP + q * 32 + quad * 8);
                lacc[mt] = __builtin_amdgcn_mfma_f32_16x16x32_bf16(a, wf, lacc[mt], 0, 0, 0);
            }
        }
        if (valid) {
            const float bias = b2[col];
#pragma unroll
            for (int mt = 0; mt < 2; ++mt)
#pragma unroll
                for (int r = 0; r < 4; ++r)
                    lg[(mt * 16 + quad * 4 + r) * 48 + col] = lacc[mt][r] + bias;
        }
    }
    __syncthreads();

    // ---- softmax per row + store ----
    if (t < LBM) {
        float* row = lg + t * 48;
        float m = row[0];
        for (int c = 1; c < NCLS; ++c) m = fmaxf(m, row[c]);
        float s = 0.0f;
        for (int c = 0; c < NCLS; ++c) { float e = expf(row[c] - m); row[c] = e; s += e; }
        const float inv = 1.0f / s;
        for (int c = 0; c < NCLS; ++c) row[c] *= inv;
    }
    __syncthreads();

    for (int i = t; i < LBM * NCLS; i += 256) {
        const int r = i / NCLS, c = i - r * NCLS;
        out[(size_t)row0 * NCLS + i] = lg[r * 48 + c];
    }
}

extern "C" void kernel_launch(void* const* d_in, const int* in_sizes, int n_in,
                              void* d_out, int out_size, void* d_ws, size_t ws_size,
                              hipStream_t stream) {
    const float* x    = (const float*)d_in[0];
    const int*  nidx  = (const int*)  d_in[1];
    const int*  vlen  = (const int*)  d_in[2];
    const float* Wemb = (const float*)d_in[3];
    const float* gW   = (const float*)d_in[4];
    const float* gB   = (const float*)d_in[5];
    const float* W1   = (const float*)d_in[6];
    const float* b1   = (const float*)d_in[7];
    const float* W2   = (const float*)d_in[8];
    const float* b2   = (const float*)d_in[9];
    float* out = (float*)d_out;

    const int nodes = 40000;
    bf16* h0 = (bf16*)d_ws;
    bf16* h1 = h0 + (size_t)nodes * HDIM;
    short* pw = (short*)(h1 + (size_t)nodes * HDIM);   // 272 KB packed weights
    const short* pwW1 = pw + 7 * 16384;
    const short* pwW2 = pw + 8 * 16384;

    // dispatch 1: embed + pack (pack ready before layer 1 by stream order)
    embed_pack<<<EGRID, 512, 0, stream>>>(x, Wemb, gW, gB, W1, W2, h0, pw);

    // dispatches 2,3: layers 1,2 (h0 -> h1 -> h0)
    layer_gemm<<<LGRID, 256, 0, stream>>>(h0, nidx, vlen, pw + 1 * 16384, pw + 4 * 16384, h1);
    layer_gemm<<<LGRID, 256, 0, stream>>>(h1, nidx, vlen, pw + 2 * 16384, pw + 5 * 16384, h0);

    // dispatch 4: layer 3 + fused classifier (no h3 global round-trip)
    layer3_cls<<<LGRID, 256, 0, stream>>>(h0, nidx, vlen, pw + 3 * 16384, pw + 6 * 16384,
                                          pwW1, b1, pwW2, b2, out);
}